// Round 7
// baseline (175.081 us; speedup 1.0000x reference)
//
#include <hip/hip_runtime.h>
#include <math.h>

// Problem constants (static per reference)
#define NPG     512
#define B_GR    512
#define FDIM    255
#define DEG     32
#define EPG     (NPG * DEG)       // 16384 edges per graph (graph-contiguous)
#define N_NODES (B_GR * NPG)      // 262144
#define E_TOT   (N_NODES * DEG)   // 8388608
#define K_KEEP  256               // ceil(0.5 * NPG)

#define CH_NODES 16                        // nodes per phase-A chunk
#define CH_FLOATS (CH_NODES * FDIM)        // 4080 floats = 16320 B
#define CH_F4     (CH_FLOATS / 4)          // 1020 float4 DMA ops per chunk
#define NCHUNK    (NPG / CH_NODES)         // 32

// direct global->LDS DMA, 16 B per lane (dest = wave-uniform base + lane*16)
__device__ __forceinline__ void lds_dma16(const void* g, void* l) {
    __builtin_amdgcn_global_load_lds(
        (const __attribute__((address_space(1))) unsigned int*)g,
        (__attribute__((address_space(3))) unsigned int*)l, 16, 0, 0);
}

// LDS-only barrier: does NOT drain vmcnt -> early-issued global loads stay
// in flight across it (they read immutable inputs; no hazard).
#define BAR_LGKM() asm volatile("s_waitcnt lgkmcnt(0)\n\ts_barrier" ::: "memory")

// ---------------------------------------------------------------------------
// One 1024-thread block per graph (512 blocks = 2/CU).
//  A: h — 2-buffer global_load_lds pipeline (unchanged from best round)
//  B: col+row int4 loads issued 8-deep -> deg -> dinv -> v=dinv*h ->
//     agg_raw[c] = v_c + sum v_r  (1 LDS read + 1 LDS atomic per edge)
//  C: score = tanh(dinv*agg_raw + b) -> float4 rank-count top-K
//  D: wave-per-row gather: 4 coalesced dword loads/row, reg accumulate,
//     LDS-atomic merge -> d_out[g, 0:256]
// ---------------------------------------------------------------------------
__global__ __launch_bounds__(1024) void k_fused(const float* __restrict__ feat,
                                                const int*   __restrict__ z,
                                                const int*   __restrict__ ei,
                                                const float* __restrict__ W,
                                                const float* __restrict__ bias,
                                                float*       __restrict__ outp) {
    __shared__ __align__(16) char stagebuf[32768]; // A: feat stage; B: col cache
    __shared__ __align__(16) float Wl[256];
    __shared__ __align__(16) float score[NPG];
    __shared__ float v_l[NPG];          // holds h, later v = dinv*h
    __shared__ float dinv_l[NPG];
    __shared__ float agg[NPG];
    __shared__ float realb[NPG];
    __shared__ int   deg[NPG];
    __shared__ int   rank2[2][NPG];     // later aliased as outacc (phase D)
    __shared__ int   selidx[K_KEEP];
    __shared__ float selsc[K_KEEP];
    __shared__ int   cnt;

    const int g     = blockIdx.x;
    const int tid   = threadIdx.x;
    const int nbase = g * NPG;
    const int lane  = tid & 63;
    const int wave  = tid >> 6;

    const int4* colp4 = (const int4*)(ei + (size_t)E_TOT + (size_t)g * EPG);
    const int4* rowp4 = (const int4*)(ei + (size_t)g * EPG);

    if (tid < 256) Wl[tid] = W[tid];
    if (tid < NPG) {
        realb[tid] = (z[nbase + tid] != 100) ? 1.f : 0.f;
        deg[tid]   = 1;                   // self-loop
    }
    if (tid == 0) cnt = 0;
    __syncthreads();

    // ---------- Phase A: projection h (2-buffer DMA pipeline) ----------
    {
        float (*stage)[CH_FLOATS] = (float (*)[CH_FLOATS])stagebuf;
        const float w0   = Wl[lane];
        const float w64  = Wl[lane + 64];
        const float w128 = Wl[lane + 128];
        const float w192 = (lane < 63) ? Wl[lane + 192] : 0.f;
        const float w255 = Wl[FDIM];
        const char* srcb = (const char*)(feat + (size_t)nbase * FDIM);

        if (tid < CH_F4)
            lds_dma16(srcb + (size_t)tid * 16, (char*)stage[0] + (size_t)tid * 16);
        asm volatile("s_waitcnt vmcnt(0)" ::: "memory");
        __builtin_amdgcn_s_barrier();
        __builtin_amdgcn_sched_barrier(0);

        for (int ch = 0; ch < NCHUNK; ++ch) {
            const float* cur = stage[ch & 1];
            float*       nxt = stage[(ch & 1) ^ 1];
            if (ch + 1 < NCHUNK && tid < CH_F4)
                lds_dma16(srcb + (size_t)(ch + 1) * 16320 + (size_t)tid * 16,
                          (char*)nxt + (size_t)tid * 16);

            const float* row = cur + wave * FDIM;
            float acc = (lane == 0) ? realb[ch * CH_NODES + wave] * w255 : 0.f;
            acc = fmaf(row[lane],       w0,   acc);
            acc = fmaf(row[lane + 64],  w64,  acc);
            acc = fmaf(row[lane + 128], w128, acc);
            if (lane < 63)
                acc = fmaf(row[lane + 192], w192, acc);
#pragma unroll
            for (int off = 32; off; off >>= 1)
                acc += __shfl_down(acc, off, 64);
            if (lane == 0) v_l[ch * CH_NODES + wave] = acc;

            asm volatile("s_waitcnt vmcnt(0)" ::: "memory");
            __builtin_amdgcn_s_barrier();
            __builtin_amdgcn_sched_barrier(0);
        }
    }
    BAR_LGKM();   // v_l (h) visible to all

    // ---------- Phase B: edges 8-deep in flight, deg, dinv, aggregate ------
    {
        ushort4* cc4 = (ushort4*)stagebuf;      // 32 KB col cache (stage done)

        int4 c4v[4], r4v[4];
#pragma unroll
        for (int it = 0; it < 4; ++it) c4v[it] = colp4[it * 1024 + tid];
#pragma unroll
        for (int it = 0; it < 4; ++it) r4v[it] = rowp4[it * 1024 + tid];

        // pass 1: col cache + in-degree (row loads still in flight)
#pragma unroll
        for (int it = 0; it < 4; ++it) {
            const int4 c4 = c4v[it];
            ushort4 u;
            u.x = (unsigned short)(c4.x - nbase);
            u.y = (unsigned short)(c4.y - nbase);
            u.z = (unsigned short)(c4.z - nbase);
            u.w = (unsigned short)(c4.w - nbase);
            cc4[it * 1024 + tid] = u;
            atomicAdd(&deg[u.x], 1);
            atomicAdd(&deg[u.y], 1);
            atomicAdd(&deg[u.z], 1);
            atomicAdd(&deg[u.w], 1);
        }
        BAR_LGKM();

        if (tid < NPG) {
            const float di = (float)(1.0 / sqrt((double)deg[tid])); // np-exact
            dinv_l[tid] = di;
            const float v = di * v_l[tid];
            v_l[tid] = v;
            agg[tid] = v;                       // self-loop term
        }
        BAR_LGKM();

        // pass 2: agg_raw[c] += v[r]   (rows already in regs)
#pragma unroll
        for (int it = 0; it < 4; ++it) {
            const ushort4 u  = cc4[it * 1024 + tid];
            const int4    r4 = r4v[it];
            atomicAdd(&agg[u.x], v_l[r4.x - nbase]);
            atomicAdd(&agg[u.y], v_l[r4.y - nbase]);
            atomicAdd(&agg[u.z], v_l[r4.z - nbase]);
            atomicAdd(&agg[u.w], v_l[r4.w - nbase]);
        }
        BAR_LGKM();
    }

    // ---------- Phase C: score + top-K selection ----------
    if (tid < NPG)
        score[tid] = tanhf(fmaf(agg[tid], dinv_l[tid], bias[0]));
    BAR_LGKM();

    {
        const int     node = tid & (NPG - 1);
        const int     half = tid >> 9;
        const float   sc   = score[node];
        const float4* s4p  = (const float4*)&score[half * 256];
        int part = 0;
#pragma unroll 8
        for (int i = 0; i < 64; ++i) {
            const float4 s4 = s4p[i];           // broadcast b128 read
            const int    j  = half * 256 + i * 4;
            part += (s4.x > sc) || (s4.x == sc && (j + 0) < node);
            part += (s4.y > sc) || (s4.y == sc && (j + 1) < node);
            part += (s4.z > sc) || (s4.z == sc && (j + 2) < node);
            part += (s4.w > sc) || (s4.w == sc && (j + 3) < node);
        }
        rank2[half][node] = part;
    }
    BAR_LGKM();

    if (tid < NPG) {
        const int rank = rank2[0][tid] + rank2[1][tid];
        if (rank < K_KEEP) {                    // jax tie-break: lower idx wins
            const int slot = atomicAdd(&cnt, 1);
            selidx[slot] = tid;
            selsc[slot]  = score[tid];
        }
    }
    BAR_LGKM();

    // ---------- Phase D: wave-per-row gather, reg accumulate ----------
    {
        float* outacc = (float*)rank2;          // alias (rank2 dead now)
        if (tid < 256) outacc[tid] = 0.f;
        BAR_LGKM();

        const float* base = feat + (size_t)nbase * FDIM;
        float a0 = 0.f, a1 = 0.f, a2 = 0.f, a3 = 0.f;
#pragma unroll 4
        for (int k = 0; k < 16; ++k) {
            const int   s   = wave + 16 * k;    // wave-uniform
            const int   idx = selidx[s];        // LDS broadcast
            const float sc  = selsc[s];
            const float* rp = base + (size_t)idx * FDIM;
            const float v0 = rp[lane];
            const float v1 = rp[lane + 64];
            const float v2 = rp[lane + 128];
            const float v3 = (lane < 63) ? rp[lane + 192] : realb[idx];
            a0 = fmaf(sc, v0, a0);
            a1 = fmaf(sc, v1, a1);
            a2 = fmaf(sc, v2, a2);
            a3 = fmaf(sc, v3, a3);
        }
        atomicAdd(&outacc[lane],       a0);
        atomicAdd(&outacc[lane + 64],  a1);
        atomicAdd(&outacc[lane + 128], a2);
        atomicAdd(&outacc[lane + 192], a3);
        BAR_LGKM();

        if (tid < 256)
            outp[(size_t)g * 256 + tid] = outacc[tid] * (1.f / K_KEEP);
    }
}

extern "C" void kernel_launch(void* const* d_in, const int* in_sizes, int n_in,
                              void* d_out, int out_size, void* d_ws, size_t ws_size,
                              hipStream_t stream) {
    const float* feat = (const float*)d_in[0];   // out: [N, F] f32
    const int*   z    = (const int*)  d_in[1];   // z:   [N] i32
    const int*   ei   = (const int*)  d_in[2];   // edge_index: [2, E] i32
    // d_in[3] = batch (unused), d_in[6] = edge_attr (unused)
    const float* W    = (const float*)d_in[4];   // [F+1] f32
    const float* bias = (const float*)d_in[5];   // [1] f32
    float* outp = (float*)d_out;                 // [B, F+1] f32

    k_fused<<<B_GR, 1024, 0, stream>>>(feat, z, ei, W, bias, outp);
}

// Round 8
// 123.260 us; speedup vs baseline: 1.4204x; 1.4204x over previous
//
#include <hip/hip_runtime.h>
#include <math.h>

// Problem constants (static per reference)
#define NPG     512
#define B_GR    512
#define FDIM    255
#define DEG     32
#define EPG     (NPG * DEG)       // 16384 edges per graph (graph-contiguous)
#define N_NODES (B_GR * NPG)      // 262144
#define E_TOT   (N_NODES * DEG)   // 8388608
#define K_KEEP  256               // ceil(0.5 * NPG)

#define CH_NODES 16                        // nodes per phase-A chunk
#define CH_FLOATS (CH_NODES * FDIM)        // 4080 floats = 16320 B
#define CH_F4     (CH_FLOATS / 4)          // 1020 float4 DMA ops per chunk
#define NCHUNK    (NPG / CH_NODES)         // 32

// direct global->LDS DMA, 16 B per lane (dest = wave-uniform base + lane*16)
__device__ __forceinline__ void lds_dma16(const void* g, void* l) {
    __builtin_amdgcn_global_load_lds(
        (const __attribute__((address_space(1))) unsigned int*)g,
        (__attribute__((address_space(3))) unsigned int*)l, 16, 0, 0);
}

// ---------------------------------------------------------------------------
// One 1024-thread block per graph (512 blocks = 2/CU).
//  A: h — 3-buffer global_load_lds pipeline, counted vmcnt(1) (depth-2)
//  B: deg (col cached as ushort in LDS) -> dinv -> v=dinv*h ->
//     agg_raw[c] = v_c + sum v_r (1 LDS read + 1 LDS atomic per edge)
//  C: score = tanh(dinv*agg_raw + b) -> float4 rank-count top-K
//  D: gated gather-mean, 8-batched static-indexed loads -> d_out[g, 0:256]
// All non-A phase boundaries use plain __syncthreads (proven structure).
// ---------------------------------------------------------------------------
__global__ __launch_bounds__(1024) void k_fused(const float* __restrict__ feat,
                                                const int*   __restrict__ z,
                                                const int*   __restrict__ ei,
                                                const float* __restrict__ W,
                                                const float* __restrict__ bias,
                                                float*       __restrict__ outp) {
    __shared__ __align__(16) float stage[3][CH_FLOATS]; // 48960 B; B: col cache
    __shared__ __align__(16) float Wl[256];
    __shared__ __align__(16) float score[NPG];
    __shared__ float v_l[NPG];          // holds h, later v = dinv*h
    __shared__ float dinv_l[NPG];
    __shared__ float agg[NPG];
    __shared__ float realb[NPG];
    __shared__ int   deg[NPG];
    __shared__ int   rank2[2][NPG];
    __shared__ int   selidx[K_KEEP];
    __shared__ float selsc[K_KEEP];
    __shared__ float red[3][256];
    __shared__ int   cnt;

    const int g     = blockIdx.x;
    const int tid   = threadIdx.x;
    const int nbase = g * NPG;
    const int lane  = tid & 63;
    const int wave  = tid >> 6;

    const int4* colp4 = (const int4*)(ei + (size_t)E_TOT + (size_t)g * EPG);
    const int4* rowp4 = (const int4*)(ei + (size_t)g * EPG);

    if (tid < 256) Wl[tid] = W[tid];
    if (tid < NPG) {
        realb[tid] = (z[nbase + tid] != 100) ? 1.f : 0.f;
        deg[tid]   = 1;                   // self-loop
    }
    if (tid == 0) cnt = 0;
    __syncthreads();

    // ---------- Phase A: projection h (3-buffer, depth-2 DMA pipeline) -----
    {
        const float w0   = Wl[lane];
        const float w64  = Wl[lane + 64];
        const float w128 = Wl[lane + 128];
        const float w192 = (lane < 63) ? Wl[lane + 192] : 0.f;
        const float w255 = Wl[FDIM];
        const char* srcb = (const char*)(feat + (size_t)nbase * FDIM);

        // prologue: chunks 0 and 1 in flight
        if (tid < CH_F4) {
            lds_dma16(srcb + (size_t)tid * 16,
                      (char*)stage[0] + (size_t)tid * 16);
            lds_dma16(srcb + 16320 + (size_t)tid * 16,
                      (char*)stage[1] + (size_t)tid * 16);
        }

        for (int ch = 0; ch < NCHUNK; ++ch) {
            // wait for chunk ch (in-order vmcnt retirement; 1 DMA instr/wave/chunk)
            if (ch == NCHUNK - 1)
                asm volatile("s_waitcnt vmcnt(0)" ::: "memory");
            else
                asm volatile("s_waitcnt vmcnt(1)" ::: "memory");
            __builtin_amdgcn_s_barrier();
            __builtin_amdgcn_sched_barrier(0);

            // issue chunk ch+2 (its buffer was consumed at iter ch-1)
            if (ch + 2 < NCHUNK && tid < CH_F4)
                lds_dma16(srcb + (size_t)(ch + 2) * 16320 + (size_t)tid * 16,
                          (char*)stage[(ch + 2) % 3] + (size_t)tid * 16);

            // dot-product for node = ch*16 + wave
            const float* row = stage[ch % 3] + wave * FDIM;
            float acc = (lane == 0) ? realb[ch * CH_NODES + wave] * w255 : 0.f;
            acc = fmaf(row[lane],       w0,   acc);
            acc = fmaf(row[lane + 64],  w64,  acc);
            acc = fmaf(row[lane + 128], w128, acc);
            if (lane < 63)
                acc = fmaf(row[lane + 192], w192, acc);
#pragma unroll
            for (int off = 32; off; off >>= 1)
                acc += __shfl_down(acc, off, 64);
            if (lane == 0) v_l[ch * CH_NODES + wave] = acc;
        }
    }
    __syncthreads();   // drain compute(31) + h writes before stage reuse

    // ---------- Phase B: degree + factored aggregation ----------
    {
        ushort4* cc4 = (ushort4*)stage;       // 32768 B col cache (fits)

        // pass 1: col cache + in-degree (4 int4 loads batched)
        int4 c4v[4];
#pragma unroll
        for (int it = 0; it < 4; ++it) c4v[it] = colp4[it * 1024 + tid];
#pragma unroll
        for (int it = 0; it < 4; ++it) {
            const int4 c4 = c4v[it];
            ushort4 u;
            u.x = (unsigned short)(c4.x - nbase);
            u.y = (unsigned short)(c4.y - nbase);
            u.z = (unsigned short)(c4.z - nbase);
            u.w = (unsigned short)(c4.w - nbase);
            cc4[it * 1024 + tid] = u;
            atomicAdd(&deg[u.x], 1);
            atomicAdd(&deg[u.y], 1);
            atomicAdd(&deg[u.z], 1);
            atomicAdd(&deg[u.w], 1);
        }
        __syncthreads();

        if (tid < NPG) {
            const float di = (float)(1.0 / sqrt((double)deg[tid])); // np-exact
            dinv_l[tid] = di;
            const float v = di * v_l[tid];
            v_l[tid] = v;
            agg[tid] = v;                     // self-loop term
        }
        __syncthreads();

        // pass 2: agg_raw[c] += v[r]  (4 int4 row loads batched)
        int4 r4v[4];
#pragma unroll
        for (int it = 0; it < 4; ++it) r4v[it] = rowp4[it * 1024 + tid];
#pragma unroll
        for (int it = 0; it < 4; ++it) {
            const ushort4 u  = cc4[it * 1024 + tid];
            const int4    r4 = r4v[it];
            atomicAdd(&agg[u.x], v_l[r4.x - nbase]);
            atomicAdd(&agg[u.y], v_l[r4.y - nbase]);
            atomicAdd(&agg[u.z], v_l[r4.z - nbase]);
            atomicAdd(&agg[u.w], v_l[r4.w - nbase]);
        }
        __syncthreads();
    }

    // ---------- Phase C: score + top-K selection ----------
    if (tid < NPG)
        score[tid] = tanhf(fmaf(agg[tid], dinv_l[tid], bias[0]));
    __syncthreads();

    {
        const int     node = tid & (NPG - 1);
        const int     half = tid >> 9;
        const float   sc   = score[node];
        const float4* s4p  = (const float4*)&score[half * 256];
        int part = 0;
#pragma unroll 8
        for (int i = 0; i < 64; ++i) {
            const float4 s4 = s4p[i];         // broadcast b128 read
            const int    j  = half * 256 + i * 4;
            part += (s4.x > sc) || (s4.x == sc && (j + 0) < node);
            part += (s4.y > sc) || (s4.y == sc && (j + 1) < node);
            part += (s4.z > sc) || (s4.z == sc && (j + 2) < node);
            part += (s4.w > sc) || (s4.w == sc && (j + 3) < node);
        }
        rank2[half][node] = part;
    }
    __syncthreads();

    if (tid < NPG) {
        const int rank = rank2[0][tid] + rank2[1][tid];
        if (rank < K_KEEP) {                  // jax tie-break: lower idx wins
            const int slot = atomicAdd(&cnt, 1);
            selidx[slot] = tid;
            selsc[slot]  = score[tid];
        }
    }
    __syncthreads();

    // ---------- Phase D: gated gather-mean (8-batched loads) ----------
    {
        const int f = tid & 255;
        const int q = tid >> 8;               // 4 quarters; s = q + 4k
        float acc = 0.f;
        if (f < FDIM) {
            const float* fb = feat + (size_t)nbase * FDIM + f;
#pragma unroll
            for (int k = 0; k < 64; k += 8) {
                int   is[8]; float ss[8]; float tv[8];
#pragma unroll
                for (int j = 0; j < 8; ++j) {
                    is[j] = selidx[q + 4 * (k + j)];
                    ss[j] = selsc [q + 4 * (k + j)];
                }
#pragma unroll
                for (int j = 0; j < 8; ++j)
                    tv[j] = fb[(size_t)is[j] * FDIM];
#pragma unroll
                for (int j = 0; j < 8; ++j)
                    acc = fmaf(ss[j], tv[j], acc);
            }
        } else {                              // f == 255: real bit
            for (int s = q; s < K_KEEP; s += 4)
                acc = fmaf(selsc[s], realb[selidx[s]], acc);
        }
        if (q) red[q - 1][f] = acc;
        __syncthreads();
        if (q == 0)
            outp[(size_t)g * 256 + f] =
                (acc + red[0][f] + red[1][f] + red[2][f]) * (1.f / K_KEEP);
    }
}

extern "C" void kernel_launch(void* const* d_in, const int* in_sizes, int n_in,
                              void* d_out, int out_size, void* d_ws, size_t ws_size,
                              hipStream_t stream) {
    const float* feat = (const float*)d_in[0];   // out: [N, F] f32
    const int*   z    = (const int*)  d_in[1];   // z:   [N] i32
    const int*   ei   = (const int*)  d_in[2];   // edge_index: [2, E] i32
    // d_in[3] = batch (unused), d_in[6] = edge_attr (unused)
    const float* W    = (const float*)d_in[4];   // [F+1] f32
    const float* bias = (const float*)d_in[5];   // [1] f32
    float* outp = (float*)d_out;                 // [B, F+1] f32

    k_fused<<<B_GR, 1024, 0, stream>>>(feat, z, ei, W, bias, outp);
}

// Round 9
// 120.974 us; speedup vs baseline: 1.4473x; 1.0189x over previous
//
#include <hip/hip_runtime.h>
#include <math.h>

// Problem constants (static per reference)
#define NPG     512
#define B_GR    512
#define FDIM    255
#define DEG     32
#define EPG     (NPG * DEG)       // 16384 edges per graph (graph-contiguous)
#define N_NODES (B_GR * NPG)      // 262144
#define E_TOT   (N_NODES * DEG)   // 8388608
#define K_KEEP  256               // ceil(0.5 * NPG)

#define CH_NODES 16                        // nodes per phase-A chunk
#define CH_FLOATS (CH_NODES * FDIM)        // 4080 floats = 16320 B
#define CH_F4     (CH_FLOATS / 4)          // 1020 float4 DMA ops per chunk
#define NCHUNK    (NPG / CH_NODES)         // 32

// direct global->LDS DMA, 16 B per lane (dest = wave-uniform base + lane*16)
__device__ __forceinline__ void lds_dma16(const void* g, void* l) {
    __builtin_amdgcn_global_load_lds(
        (const __attribute__((address_space(1))) unsigned int*)g,
        (__attribute__((address_space(3))) unsigned int*)l, 16, 0, 0);
}

// ---------------------------------------------------------------------------
// One 1024-thread block per graph; __launch_bounds__(1024,8) pins 2 blocks/CU
// while raising the VGPR cap 24 -> 64 so batched loads stay in registers.
//  A: h — 2-buffer global_load_lds pipeline (R4-proven order)
//  B: deg (col cached as ushort) -> dinv -> v=dinv*h -> agg[c] = v_c + sum v_r
//  C: score = tanh(dinv*agg + b) -> float4 rank-count top-K (jax tie-break)
//  D: gated gather-mean, 8-batched register-resident loads -> d_out[g, 0:256]
// ---------------------------------------------------------------------------
__global__ __launch_bounds__(1024, 8) void k_fused(const float* __restrict__ feat,
                                                   const int*   __restrict__ z,
                                                   const int*   __restrict__ ei,
                                                   const float* __restrict__ W,
                                                   const float* __restrict__ bias,
                                                   float*       __restrict__ outp) {
    // phase A: 2 x 16320 B stage; phase B: 32768 B ushort col cache
    __shared__ __align__(16) char stagebuf[32768];
    __shared__ __align__(16) float Wl[256];
    __shared__ __align__(16) float score[NPG];
    __shared__ float v_l[NPG];          // holds h, later v = dinv*h
    __shared__ float dinv_l[NPG];
    __shared__ float agg[NPG];
    __shared__ float realb[NPG];
    __shared__ int   deg[NPG];
    __shared__ int   rank2[2][NPG];
    __shared__ int   selidx[K_KEEP];
    __shared__ float selsc[K_KEEP];
    __shared__ float red[3][256];
    __shared__ int   cnt;

    const int g     = blockIdx.x;
    const int tid   = threadIdx.x;
    const int nbase = g * NPG;
    const int lane  = tid & 63;
    const int wave  = tid >> 6;

    const int4* colp4 = (const int4*)(ei + (size_t)E_TOT + (size_t)g * EPG);
    const int4* rowp4 = (const int4*)(ei + (size_t)g * EPG);

    if (tid < 256) Wl[tid] = W[tid];
    if (tid < NPG) {
        realb[tid] = (z[nbase + tid] != 100) ? 1.f : 0.f;
        deg[tid]   = 1;                   // self-loop
    }
    if (tid == 0) cnt = 0;
    __syncthreads();

    // ---------- Phase A: projection h (2-buffer DMA pipeline, R4 order) ----
    {
        float (*stage)[CH_FLOATS] = (float (*)[CH_FLOATS])stagebuf;
        const float w0   = Wl[lane];
        const float w64  = Wl[lane + 64];
        const float w128 = Wl[lane + 128];
        const float w192 = (lane < 63) ? Wl[lane + 192] : 0.f;
        const float w255 = Wl[FDIM];
        const char* srcb = (const char*)(feat + (size_t)nbase * FDIM);

        // prologue: stage chunk 0
        if (tid < CH_F4)
            lds_dma16(srcb + (size_t)tid * 16, (char*)stage[0] + (size_t)tid * 16);
        asm volatile("s_waitcnt vmcnt(0)" ::: "memory");
        __builtin_amdgcn_s_barrier();
        __builtin_amdgcn_sched_barrier(0);

        for (int ch = 0; ch < NCHUNK; ++ch) {
            const float* cur = stage[ch & 1];
            float*       nxt = (float*)stage[(ch & 1) ^ 1];
            if (ch + 1 < NCHUNK && tid < CH_F4)
                lds_dma16(srcb + (size_t)(ch + 1) * 16320 + (size_t)tid * 16,
                          (char*)nxt + (size_t)tid * 16);

            // dot-product for node = ch*16 + wave
            const float* row = cur + wave * FDIM;
            float acc = (lane == 0) ? realb[ch * CH_NODES + wave] * w255 : 0.f;
            acc = fmaf(row[lane],       w0,   acc);
            acc = fmaf(row[lane + 64],  w64,  acc);
            acc = fmaf(row[lane + 128], w128, acc);
            if (lane < 63)
                acc = fmaf(row[lane + 192], w192, acc);
#pragma unroll
            for (int off = 32; off; off >>= 1)
                acc += __shfl_down(acc, off, 64);
            if (lane == 0) v_l[ch * CH_NODES + wave] = acc;

            asm volatile("s_waitcnt vmcnt(0)" ::: "memory"); // next chunk landed
            __builtin_amdgcn_s_barrier();
            __builtin_amdgcn_sched_barrier(0);
        }
    }
    __syncthreads();   // h visible; stage reusable

    // ---------- Phase B: degree + factored aggregation ----------
    {
        ushort4* cc4 = (ushort4*)stagebuf;    // 32768 B col cache (fits)

        // pass 1: col cache + in-degree (4 int4 loads batched in regs)
        int4 c4v[4];
#pragma unroll
        for (int it = 0; it < 4; ++it) c4v[it] = colp4[it * 1024 + tid];
#pragma unroll
        for (int it = 0; it < 4; ++it) {
            const int4 c4 = c4v[it];
            ushort4 u;
            u.x = (unsigned short)(c4.x - nbase);
            u.y = (unsigned short)(c4.y - nbase);
            u.z = (unsigned short)(c4.z - nbase);
            u.w = (unsigned short)(c4.w - nbase);
            cc4[it * 1024 + tid] = u;
            atomicAdd(&deg[u.x], 1);
            atomicAdd(&deg[u.y], 1);
            atomicAdd(&deg[u.z], 1);
            atomicAdd(&deg[u.w], 1);
        }
        __syncthreads();

        if (tid < NPG) {
            const float di = (float)(1.0 / sqrt((double)deg[tid])); // np-exact
            dinv_l[tid] = di;
            const float v = di * v_l[tid];
            v_l[tid] = v;
            agg[tid] = v;                     // self-loop term
        }
        __syncthreads();

        // pass 2: agg_raw[c] += v[r]  (4 int4 row loads batched in regs)
        int4 r4v[4];
#pragma unroll
        for (int it = 0; it < 4; ++it) r4v[it] = rowp4[it * 1024 + tid];
#pragma unroll
        for (int it = 0; it < 4; ++it) {
            const ushort4 u  = cc4[it * 1024 + tid];
            const int4    r4 = r4v[it];
            atomicAdd(&agg[u.x], v_l[r4.x - nbase]);
            atomicAdd(&agg[u.y], v_l[r4.y - nbase]);
            atomicAdd(&agg[u.z], v_l[r4.z - nbase]);
            atomicAdd(&agg[u.w], v_l[r4.w - nbase]);
        }
        __syncthreads();
    }

    // ---------- Phase C: score + top-K selection ----------
    if (tid < NPG)
        score[tid] = tanhf(fmaf(agg[tid], dinv_l[tid], bias[0]));
    __syncthreads();

    {
        const int     node = tid & (NPG - 1);
        const int     half = tid >> 9;
        const float   sc   = score[node];
        const float4* s4p  = (const float4*)&score[half * 256];
        int part = 0;
#pragma unroll 8
        for (int i = 0; i < 64; ++i) {
            const float4 s4 = s4p[i];         // broadcast b128 read
            const int    j  = half * 256 + i * 4;
            part += (s4.x > sc) || (s4.x == sc && (j + 0) < node);
            part += (s4.y > sc) || (s4.y == sc && (j + 1) < node);
            part += (s4.z > sc) || (s4.z == sc && (j + 2) < node);
            part += (s4.w > sc) || (s4.w == sc && (j + 3) < node);
        }
        rank2[half][node] = part;
    }
    __syncthreads();

    if (tid < NPG) {
        const int rank = rank2[0][tid] + rank2[1][tid];
        if (rank < K_KEEP) {                  // jax tie-break: lower idx wins
            const int slot = atomicAdd(&cnt, 1);
            selidx[slot] = tid;
            selsc[slot]  = score[tid];
        }
    }
    __syncthreads();

    // ---------- Phase D: gated gather-mean (8-batched, reg-resident) ------
    {
        const int f = tid & 255;
        const int q = tid >> 8;               // 4 quarters; s = q + 4k
        float acc = 0.f;
        if (f < FDIM) {
            const float* fb = feat + (size_t)nbase * FDIM + f;
#pragma unroll
            for (int k = 0; k < 64; k += 8) {
                int   is[8]; float ss[8]; float tv[8];
#pragma unroll
                for (int j = 0; j < 8; ++j) {
                    is[j] = selidx[q + 4 * (k + j)];
                    ss[j] = selsc [q + 4 * (k + j)];
                }
#pragma unroll
                for (int j = 0; j < 8; ++j)
                    tv[j] = fb[(size_t)is[j] * FDIM];
#pragma unroll
                for (int j = 0; j < 8; ++j)
                    acc = fmaf(ss[j], tv[j], acc);
            }
        } else {                              // f == 255: real bit
            for (int s = q; s < K_KEEP; s += 4)
                acc = fmaf(selsc[s], realb[selidx[s]], acc);
        }
        if (q) red[q - 1][f] = acc;
        __syncthreads();
        if (q == 0)
            outp[(size_t)g * 256 + f] =
                (acc + red[0][f] + red[1][f] + red[2][f]) * (1.f / K_KEEP);
    }
}

extern "C" void kernel_launch(void* const* d_in, const int* in_sizes, int n_in,
                              void* d_out, int out_size, void* d_ws, size_t ws_size,
                              hipStream_t stream) {
    const float* feat = (const float*)d_in[0];   // out: [N, F] f32
    const int*   z    = (const int*)  d_in[1];   // z:   [N] i32
    const int*   ei   = (const int*)  d_in[2];   // edge_index: [2, E] i32
    // d_in[3] = batch (unused), d_in[6] = edge_attr (unused)
    const float* W    = (const float*)d_in[4];   // [F+1] f32
    const float* bias = (const float*)d_in[5];   // [1] f32
    float* outp = (float*)d_out;                 // [B, F+1] f32

    k_fused<<<B_GR, 1024, 0, stream>>>(feat, z, ei, W, bias, outp);
}